// Round 1
// baseline (90.868 us; speedup 1.0000x reference)
//
#include <hip/hip_runtime.h>
#include <hip/hip_bf16.h>

// Problem constants (reference: B=128, K=2048, D=512, c=1.0)
#define B_SZ 128
#define K_SZ 2048
#define D_SZ 512

// GEMM tiling
#define BM 32      // b-tile
#define BN 32      // k-tile
#define BD 64      // d-chunk
#define LDSS 68    // LDS row stride in floats (64 + 4 pad, keeps 16B align)

// Kernel 1: per-row scalars.
// rows [0,K): uu[k]=||p_k||^2, nua[k]=-<p_k,a_k>, an[k]=||a_k||
// rows [K,K+B): vv[b]=||x_b||^2
// One wave (64 lanes) per row; D=512 -> 2 float4 per lane.
__global__ __launch_bounds__(256) void stats_kernel(
    const float* __restrict__ x, const float* __restrict__ p,
    const float* __restrict__ a, float* __restrict__ uu,
    float* __restrict__ nua, float* __restrict__ an, float* __restrict__ vv) {
  int gw = (blockIdx.x * 256 + threadIdx.x) >> 6;
  int lane = threadIdx.x & 63;
  if (gw < K_SZ) {
    const float4* pr = (const float4*)(p + (size_t)gw * D_SZ);
    const float4* ar = (const float4*)(a + (size_t)gw * D_SZ);
    float pp = 0.f, pa = 0.f, aa = 0.f;
#pragma unroll
    for (int i = 0; i < 2; ++i) {
      float4 pv = pr[lane + 64 * i];
      float4 av = ar[lane + 64 * i];
      pp += pv.x * pv.x + pv.y * pv.y + pv.z * pv.z + pv.w * pv.w;
      pa += pv.x * av.x + pv.y * av.y + pv.z * av.z + pv.w * av.w;
      aa += av.x * av.x + av.y * av.y + av.z * av.z + av.w * av.w;
    }
#pragma unroll
    for (int off = 32; off > 0; off >>= 1) {
      pp += __shfl_xor(pp, off, 64);
      pa += __shfl_xor(pa, off, 64);
      aa += __shfl_xor(aa, off, 64);
    }
    if (lane == 0) {
      uu[gw] = pp;
      nua[gw] = -pa;
      an[gw] = sqrtf(aa);
    }
  } else if (gw < K_SZ + B_SZ) {
    int b = gw - K_SZ;
    const float4* xr = (const float4*)(x + (size_t)b * D_SZ);
    float s = 0.f;
#pragma unroll
    for (int i = 0; i < 2; ++i) {
      float4 xv = xr[lane + 64 * i];
      s += xv.x * xv.x + xv.y * xv.y + xv.z * xv.z + xv.w * xv.w;
    }
#pragma unroll
    for (int off = 32; off > 0; off >>= 1) s += __shfl_xor(s, off, 64);
    if (lane == 0) vv[b] = s;
  }
}

// Kernel 2: dual GEMM (s=<x,p>, xa=<x,a>) + hyperbolic-MLR epilogue.
// Grid: (B/BM)*(K/BN) = 4*64 = 256 blocks. 256 threads.
// Thread tile: 4 b's x 1 k  (kx = t&31 -> k, by = t>>5 -> b group of 4).
// LDS: row-major [row][d] with stride 68 + XOR swizzle on the float4 index
// (rows differing by 8 get distinct bank quads -> no 4-way conflicts).
__global__ __launch_bounds__(256) void gemm_epi_kernel(
    const float* __restrict__ x, const float* __restrict__ p,
    const float* __restrict__ a, const float* __restrict__ uu,
    const float* __restrict__ nua, const float* __restrict__ an,
    const float* __restrict__ vv, float* __restrict__ out) {
  __shared__ float xs[BM * LDSS];
  __shared__ float ps[BN * LDSS];
  __shared__ float as2[BN * LDSS];
  const int t = threadIdx.x;
  const int bm = (blockIdx.x & 3) * BM;
  const int bn = (blockIdx.x >> 2) * BN;
  const int kx = t & 31;
  const int by = t >> 5;

  float acc_s[4] = {0.f, 0.f, 0.f, 0.f};   // sum x*p
  float acc_xa[4] = {0.f, 0.f, 0.f, 0.f};  // sum x*a

  for (int d0 = 0; d0 < D_SZ; d0 += BD) {
    __syncthreads();  // previous chunk fully consumed before overwrite
#pragma unroll
    for (int pass = 0; pass < 2; ++pass) {
      int idx = t + pass * 256;
      int row = idx >> 4;         // 0..31
      int col = (idx & 15) << 2;  // 0,4,...,60
      int sw = col ^ (((row >> 3) & 3) << 2);
      *(float4*)&xs[row * LDSS + sw] =
          *(const float4*)(x + (size_t)(bm + row) * D_SZ + d0 + col);
      *(float4*)&ps[row * LDSS + sw] =
          *(const float4*)(p + (size_t)(bn + row) * D_SZ + d0 + col);
      *(float4*)&as2[row * LDSS + sw] =
          *(const float4*)(a + (size_t)(bn + row) * D_SZ + d0 + col);
    }
    __syncthreads();
#pragma unroll
    for (int dd = 0; dd < BD; dd += 4) {
      int swk = dd ^ (((kx >> 3) & 3) << 2);
      float4 pv = *(const float4*)&ps[kx * LDSS + swk];
      float4 av = *(const float4*)&as2[kx * LDSS + swk];
#pragma unroll
      for (int j = 0; j < 4; ++j) {
        int r = 4 * by + j;
        float4 xv = *(const float4*)&xs[r * LDSS + (dd ^ (((r >> 3) & 3) << 2))];
        acc_s[j] += xv.x * pv.x + xv.y * pv.y + xv.z * pv.z + xv.w * pv.w;
        acc_xa[j] += xv.x * av.x + xv.y * av.y + xv.z * av.z + xv.w * av.w;
      }
    }
  }

  // Epilogue: c = 1, sqrt(c) = 1.
  const int k = bn + kx;
  const float uuk = uu[k];
  const float nuak = nua[k];
  const float ank = an[k];
  const float beta = 1.f - uuk;            // 1 - c*uu
  const float scale = (2.f / beta) * ank;  // lam_p * ||a|| / sqrt(c)
#pragma unroll
  for (int j = 0; j < 4; ++j) {
    const int b = bm + 4 * by + j;
    const float vvb = vv[b];
    const float uv = -acc_s[j];   // <u,x> = -<p,x>
    const float xa = acc_xa[j];
    const float alpha = 1.f + 2.f * uv + vvb;
    const float den = 1.f + 2.f * uv + uuk * vvb;
    const float inv_den = 1.f / den;
    const float ww =
        (alpha * alpha * uuk + 2.f * alpha * beta * uv + beta * beta * vvb) *
        inv_den * inv_den;
    const float wa = (alpha * nuak + beta * xa) * inv_den;
    const float z = 2.f * wa / (ank * (1.f - ww));
    out[(size_t)b * K_SZ + k] = scale * asinhf(z);
  }
}

extern "C" void kernel_launch(void* const* d_in, const int* in_sizes, int n_in,
                              void* d_out, int out_size, void* d_ws, size_t ws_size,
                              hipStream_t stream) {
  const float* x = (const float*)d_in[0];  // inp [B,D]
  const float* p = (const float*)d_in[1];  // p   [K,D]
  const float* a = (const float*)d_in[2];  // a   [K,D]
  float* out = (float*)d_out;              // [B,K] fp32
  float* ws = (float*)d_ws;
  float* uu = ws;               // [K]
  float* nua = ws + K_SZ;       // [K]
  float* an = ws + 2 * K_SZ;    // [K]
  float* vv = ws + 3 * K_SZ;    // [B]

  stats_kernel<<<(K_SZ + B_SZ) / 4, 256, 0, stream>>>(x, p, a, uu, nua, an, vv);
  gemm_epi_kernel<<<(B_SZ / BM) * (K_SZ / BN), 256, 0, stream>>>(
      x, p, a, uu, nua, an, vv, out);
}

// Round 2
// 72.945 us; speedup vs baseline: 1.2457x; 1.2457x over previous
//
#include <hip/hip_runtime.h>
#include <hip/hip_bf16.h>

// Problem constants (reference: B=128, K=2048, D=512, c=1.0)
#define B_SZ 128
#define K_SZ 2048
#define D_SZ 512

typedef __attribute__((ext_vector_type(8))) short short8;   // 8 bf16 = 4 VGPRs
typedef __attribute__((ext_vector_type(4))) float floatx4;  // MFMA accumulator

// Workspace layout (bytes):
//   uu  @ 0        : K fp32  (8192)
//   nua @ 8192     : K fp32
//   an  @ 16384    : K fp32
//   vv  @ 24576    : B fp32  (512)
//   xb  @ 25088    : B*D bf16 (131072)
//   pb  @ 156160   : K*D bf16 (2097152)
//   ab  @ 2253312  : K*D bf16 (2097152)
// total ~4.15 MB

// Manual RNE fp32 -> bf16 (3 VALU ops, no NaN concerns for this data).
static __device__ inline unsigned short f2b(float f) {
  unsigned int u = __float_as_uint(f);
  return (unsigned short)((u + 0x7fffu + ((u >> 16) & 1u)) >> 16);
}

// Kernel 1: per-row scalars (fp32) + bf16 conversion of x,p,a.
// One wave per row. rows [0,K): p/a rows; rows [K,K+B): x rows.
__global__ __launch_bounds__(256) void prep_kernel(
    const float* __restrict__ x, const float* __restrict__ p,
    const float* __restrict__ a, float* __restrict__ uu,
    float* __restrict__ nua, float* __restrict__ an, float* __restrict__ vv,
    unsigned short* __restrict__ xb, unsigned short* __restrict__ pb,
    unsigned short* __restrict__ ab) {
  int gw = (blockIdx.x * 256 + threadIdx.x) >> 6;
  int lane = threadIdx.x & 63;
  if (gw < K_SZ) {
    const float4* pr = (const float4*)(p + (size_t)gw * D_SZ);
    const float4* ar = (const float4*)(a + (size_t)gw * D_SZ);
    float pp = 0.f, pa = 0.f, aa = 0.f;
#pragma unroll
    for (int i = 0; i < 2; ++i) {
      float4 pv = pr[lane + 64 * i];
      float4 av = ar[lane + 64 * i];
      pp += pv.x * pv.x + pv.y * pv.y + pv.z * pv.z + pv.w * pv.w;
      pa += pv.x * av.x + pv.y * av.y + pv.z * av.z + pv.w * av.w;
      aa += av.x * av.x + av.y * av.y + av.z * av.z + av.w * av.w;
      ushort4 pc, ac;
      pc.x = f2b(pv.x); pc.y = f2b(pv.y); pc.z = f2b(pv.z); pc.w = f2b(pv.w);
      ac.x = f2b(av.x); ac.y = f2b(av.y); ac.z = f2b(av.z); ac.w = f2b(av.w);
      *(ushort4*)(pb + (size_t)gw * D_SZ + (size_t)(lane + 64 * i) * 4) = pc;
      *(ushort4*)(ab + (size_t)gw * D_SZ + (size_t)(lane + 64 * i) * 4) = ac;
    }
#pragma unroll
    for (int off = 32; off > 0; off >>= 1) {
      pp += __shfl_xor(pp, off, 64);
      pa += __shfl_xor(pa, off, 64);
      aa += __shfl_xor(aa, off, 64);
    }
    if (lane == 0) {
      uu[gw] = pp;
      nua[gw] = -pa;
      an[gw] = sqrtf(aa);
    }
  } else if (gw < K_SZ + B_SZ) {
    int b = gw - K_SZ;
    const float4* xr = (const float4*)(x + (size_t)b * D_SZ);
    float s = 0.f;
#pragma unroll
    for (int i = 0; i < 2; ++i) {
      float4 xv = xr[lane + 64 * i];
      s += xv.x * xv.x + xv.y * xv.y + xv.z * xv.z + xv.w * xv.w;
      ushort4 xc;
      xc.x = f2b(xv.x); xc.y = f2b(xv.y); xc.z = f2b(xv.z); xc.w = f2b(xv.w);
      *(ushort4*)(xb + (size_t)b * D_SZ + (size_t)(lane + 64 * i) * 4) = xc;
    }
#pragma unroll
    for (int off = 32; off > 0; off >>= 1) s += __shfl_xor(s, off, 64);
    if (lane == 0) vv[b] = s;
  }
}

// Kernel 2: bf16-MFMA dual GEMM + hyperbolic-MLR epilogue.
// 1024 independent waves (256 blocks x 4 waves): wave = one 16(b) x 16(k)
// tile, both dots. No LDS, no barriers. A (x rows) preloaded into 64 VGPRs;
// p/a fragments streamed from global (L2-resident; rows reused 8x across
// m-tiles, x reused via L1 across the block's 4 waves).
// Fragment layouts (guide §3, m89/m91-verified):
//   A: m = lane&15, k(d) = (lane>>4)*8 + j   (16B contiguous per lane)
//   B: n = lane&15, k(d) = (lane>>4)*8 + j   (p/a row-major is exactly B^T)
//   C/D: col(n) = lane&15, row(m) = (lane>>4)*4 + reg
__global__ __launch_bounds__(256) void mfma_kernel(
    const unsigned short* __restrict__ xb, const unsigned short* __restrict__ pb,
    const unsigned short* __restrict__ ab, const float* __restrict__ uu,
    const float* __restrict__ nua, const float* __restrict__ an,
    const float* __restrict__ vv, float* __restrict__ out) {
  const int t = threadIdx.x;
  const int wave = t >> 6;
  const int lane = t & 63;
  const int row16 = lane & 15;
  const int quad = lane >> 4;
  const int mt = blockIdx.x & 7;   // 8 m-tiles of 16 b's
  const int kg = blockIdx.x >> 3;  // 32 k-groups
  const int kt = kg * 4 + wave;    // 128 k-tiles of 16 k's
  const int bm = mt * 16;
  const int kn = kt * 16;

  // A preload: 16 d-chunks of 32, 16B/lane each.
  const short8* arow = (const short8*)(xb + (size_t)(bm + row16) * D_SZ) + quad;
  short8 afrag[16];
#pragma unroll
  for (int dc = 0; dc < 16; ++dc) afrag[dc] = arow[dc * 4];

  const short8* prow = (const short8*)(pb + (size_t)(kn + row16) * D_SZ) + quad;
  const short8* brow = (const short8*)(ab + (size_t)(kn + row16) * D_SZ) + quad;

  floatx4 cs = {0.f, 0.f, 0.f, 0.f};  // <x,p>
  floatx4 ca = {0.f, 0.f, 0.f, 0.f};  // <x,a>
#pragma unroll
  for (int dc = 0; dc < 16; ++dc) {
    short8 bp = prow[dc * 4];
    short8 bv = brow[dc * 4];
    cs = __builtin_amdgcn_mfma_f32_16x16x32_bf16(afrag[dc], bp, cs, 0, 0, 0);
    ca = __builtin_amdgcn_mfma_f32_16x16x32_bf16(afrag[dc], bv, ca, 0, 0, 0);
  }

  // Epilogue (c = 1): per lane, 4 outputs (b = bm + quad*4 + r, k = kn + col).
  const int k = kn + row16;
  const float uuk = uu[k];
  const float nuak = nua[k];
  const float ank = an[k];
  const float beta = 1.f - uuk;            // 1 - c*||p||^2
  const float scale = (2.f / beta) * ank;  // lam_p * ||a||
#pragma unroll
  for (int r = 0; r < 4; ++r) {
    const int b = bm + quad * 4 + r;
    const float vvb = vv[b];
    const float uv = -cs[r];  // <u,x> = -<p,x>
    const float xa = ca[r];
    const float alpha = 1.f + 2.f * uv + vvb;
    const float den = 1.f + 2.f * uv + uuk * vvb;
    const float inv = 1.f / den;
    const float ww =
        (alpha * alpha * uuk + 2.f * alpha * beta * uv + beta * beta * vvb) *
        inv * inv;
    const float wa = (alpha * nuak + beta * xa) * inv;
    const float z = 2.f * wa / (ank * (1.f - ww));
    out[(size_t)b * K_SZ + k] = scale * asinhf(z);
  }
}

extern "C" void kernel_launch(void* const* d_in, const int* in_sizes, int n_in,
                              void* d_out, int out_size, void* d_ws, size_t ws_size,
                              hipStream_t stream) {
  const float* x = (const float*)d_in[0];  // inp [B,D]
  const float* p = (const float*)d_in[1];  // p   [K,D]
  const float* a = (const float*)d_in[2];  // a   [K,D]
  float* out = (float*)d_out;              // [B,K] fp32

  char* ws = (char*)d_ws;
  float* uu = (float*)(ws + 0);
  float* nua = (float*)(ws + 8192);
  float* an = (float*)(ws + 16384);
  float* vv = (float*)(ws + 24576);
  unsigned short* xb = (unsigned short*)(ws + 25088);
  unsigned short* pb = (unsigned short*)(ws + 156160);
  unsigned short* ab = (unsigned short*)(ws + 2253312);

  prep_kernel<<<(K_SZ + B_SZ) / 4, 256, 0, stream>>>(x, p, a, uu, nua, an, vv,
                                                     xb, pb, ab);
  mfma_kernel<<<(B_SZ / 16) * (K_SZ / 16) / 4, 256, 0, stream>>>(
      xb, pb, ab, uu, nua, an, vv, out);
}

// Round 3
// 69.964 us; speedup vs baseline: 1.2988x; 1.0426x over previous
//
#include <hip/hip_runtime.h>
#include <hip/hip_bf16.h>

// Problem constants (reference: B=128, K=2048, D=512, c=1.0)
#define B_SZ 128
#define K_SZ 2048
#define D_SZ 512

typedef __attribute__((ext_vector_type(8))) short short8;   // 8 bf16 = 4 VGPRs
typedef __attribute__((ext_vector_type(4))) float floatx4;  // MFMA accumulator

// Workspace layout (bytes):
//   uu  @ 0        : K fp32  (8192)
//   nua @ 8192     : K fp32
//   an  @ 16384    : K fp32
//   vv  @ 24576    : B fp32  (512)
//   xb  @ 25088    : B*D bf16 (131072)
//   pb  @ 156160   : K*D bf16 (2097152)
//   ab  @ 2253312  : K*D bf16 (2097152)
// total ~4.15 MB (<< ws_size)

// Manual RNE fp32 -> bf16.
static __device__ inline unsigned short f2b(float f) {
  unsigned int u = __float_as_uint(f);
  return (unsigned short)((u + 0x7fffu + ((u >> 16) & 1u)) >> 16);
}

// Kernel 1: per-row scalars (fp32) + bf16 conversion of x,p,a.
// One wave per row. rows [0,K): p/a rows; rows [K,K+B): x rows.
__global__ __launch_bounds__(256) void prep_kernel(
    const float* __restrict__ x, const float* __restrict__ p,
    const float* __restrict__ a, float* __restrict__ uu,
    float* __restrict__ nua, float* __restrict__ an, float* __restrict__ vv,
    unsigned short* __restrict__ xb, unsigned short* __restrict__ pb,
    unsigned short* __restrict__ ab) {
  int gw = (blockIdx.x * 256 + threadIdx.x) >> 6;
  int lane = threadIdx.x & 63;
  if (gw < K_SZ) {
    const float4* pr = (const float4*)(p + (size_t)gw * D_SZ);
    const float4* ar = (const float4*)(a + (size_t)gw * D_SZ);
    float pp = 0.f, pa = 0.f, aa = 0.f;
#pragma unroll
    for (int i = 0; i < 2; ++i) {
      float4 pv = pr[lane + 64 * i];
      float4 av = ar[lane + 64 * i];
      pp += pv.x * pv.x + pv.y * pv.y + pv.z * pv.z + pv.w * pv.w;
      pa += pv.x * av.x + pv.y * av.y + pv.z * av.z + pv.w * av.w;
      aa += av.x * av.x + av.y * av.y + av.z * av.z + av.w * av.w;
      ushort4 pc, ac;
      pc.x = f2b(pv.x); pc.y = f2b(pv.y); pc.z = f2b(pv.z); pc.w = f2b(pv.w);
      ac.x = f2b(av.x); ac.y = f2b(av.y); ac.z = f2b(av.z); ac.w = f2b(av.w);
      *(ushort4*)(pb + (size_t)gw * D_SZ + (size_t)(lane + 64 * i) * 4) = pc;
      *(ushort4*)(ab + (size_t)gw * D_SZ + (size_t)(lane + 64 * i) * 4) = ac;
    }
#pragma unroll
    for (int off = 32; off > 0; off >>= 1) {
      pp += __shfl_xor(pp, off, 64);
      pa += __shfl_xor(pa, off, 64);
      aa += __shfl_xor(aa, off, 64);
    }
    if (lane == 0) {
      uu[gw] = pp;
      nua[gw] = -pa;
      an[gw] = sqrtf(aa);
    }
  } else if (gw < K_SZ + B_SZ) {
    int b = gw - K_SZ;
    const float4* xr = (const float4*)(x + (size_t)b * D_SZ);
    float s = 0.f;
#pragma unroll
    for (int i = 0; i < 2; ++i) {
      float4 xv = xr[lane + 64 * i];
      s += xv.x * xv.x + xv.y * xv.y + xv.z * xv.z + xv.w * xv.w;
      ushort4 xc;
      xc.x = f2b(xv.x); xc.y = f2b(xv.y); xc.z = f2b(xv.z); xc.w = f2b(xv.w);
      *(ushort4*)(xb + (size_t)b * D_SZ + (size_t)(lane + 64 * i) * 4) = xc;
    }
#pragma unroll
    for (int off = 32; off > 0; off >>= 1) s += __shfl_xor(s, off, 64);
    if (lane == 0) vv[b] = s;
  }
}

// Kernel 2: bf16-MFMA dual GEMM + epilogue, D-split across 4 waves.
// 1024 blocks (4/CU -> 4 waves/SIMD), 256 threads. Block = one 16(b)x16(k)
// output tile; wave w accumulates d in [128w, 128w+128) (4 MFMA steps x 2
// dots), partials combined through LDS, then each thread computes ONE logit.
// Block->tile map kt = blk&127: all 8 m-tiles of a k-tile land on one XCD
// (1024 blocks round-robin over 8 XCDs) -> p/a fetched once per XCD.
// Fragment layouts (m89/m91-verified):
//   A: m = lane&15, d = (lane>>4)*8 + j ; B: n = lane&15, same d (row-major
//   p/a == B^T). C/D: n = lane&15, m = (lane>>4)*4 + reg.
__global__ __launch_bounds__(256, 4) void mfma_kernel(
    const unsigned short* __restrict__ xb, const unsigned short* __restrict__ pb,
    const unsigned short* __restrict__ ab, const float* __restrict__ uu,
    const float* __restrict__ nua, const float* __restrict__ an,
    const float* __restrict__ vv, float* __restrict__ out) {
  __shared__ float rs[4 * 256];  // <x,p> partials: [wave][lane][reg]
  __shared__ float ra[4 * 256];  // <x,a> partials
  const int t = threadIdx.x;
  const int w = t >> 6;
  const int lane = t & 63;
  const int row16 = lane & 15;
  const int quad = lane >> 4;
  const int mt = blockIdx.x >> 7;   // 8 m-tiles
  const int kt = blockIdx.x & 127;  // 128 k-tiles
  const int bm = mt * 16;
  const int kn = kt * 16;
  const int d0 = w * 128;  // this wave's D-slice

  const short8* arow =
      (const short8*)(xb + (size_t)(bm + row16) * D_SZ + d0) + quad;
  const short8* prow =
      (const short8*)(pb + (size_t)(kn + row16) * D_SZ + d0) + quad;
  const short8* brow =
      (const short8*)(ab + (size_t)(kn + row16) * D_SZ + d0) + quad;

  short8 af[4], bp[4], bv[4];
#pragma unroll
  for (int dc = 0; dc < 4; ++dc) {
    af[dc] = arow[dc * 4];
    bp[dc] = prow[dc * 4];
    bv[dc] = brow[dc * 4];
  }

  floatx4 cs = {0.f, 0.f, 0.f, 0.f};
  floatx4 ca = {0.f, 0.f, 0.f, 0.f};
#pragma unroll
  for (int dc = 0; dc < 4; ++dc) {
    cs = __builtin_amdgcn_mfma_f32_16x16x32_bf16(af[dc], bp[dc], cs, 0, 0, 0);
    ca = __builtin_amdgcn_mfma_f32_16x16x32_bf16(af[dc], bv[dc], ca, 0, 0, 0);
  }

  // Partials to LDS: b128 per lane, banks stride 4 -> 2-way (free).
  *(floatx4*)&rs[t * 4] = cs;
  *(floatx4*)&ra[t * 4] = ca;
  __syncthreads();

  // Thread t -> one output (m = t>>4, n = t&15).
  const int m = t >> 4;
  const int n = t & 15;
  const int src = ((m >> 2) * 16 + n) * 4 + (m & 3);  // [lane][reg] of partial
  float sdot = 0.f, adot = 0.f;
#pragma unroll
  for (int ww_ = 0; ww_ < 4; ++ww_) {
    sdot += rs[ww_ * 256 + src];
    adot += ra[ww_ * 256 + src];
  }

  // Epilogue (c = 1).
  const int k = kn + n;
  const int b = bm + m;
  const float uuk = uu[k];
  const float nuak = nua[k];
  const float ank = an[k];
  const float vvb = vv[b];
  const float beta = 1.f - uuk;            // 1 - c*||p||^2
  const float scale = (2.f / beta) * ank;  // lam_p * ||a||
  const float uv = -sdot;                  // <u,x> = -<p,x>
  const float alpha = 1.f + 2.f * uv + vvb;
  const float den = 1.f + 2.f * uv + uuk * vvb;
  const float inv = 1.f / den;
  const float wwn =
      (alpha * alpha * uuk + 2.f * alpha * beta * uv + beta * beta * vvb) *
      inv * inv;
  const float wa = (alpha * nuak + beta * adot) * inv;
  const float z = 2.f * wa / (ank * (1.f - wwn));
  out[(size_t)b * K_SZ + k] = scale * asinhf(z);
}

extern "C" void kernel_launch(void* const* d_in, const int* in_sizes, int n_in,
                              void* d_out, int out_size, void* d_ws, size_t ws_size,
                              hipStream_t stream) {
  const float* x = (const float*)d_in[0];  // inp [B,D]
  const float* p = (const float*)d_in[1];  // p   [K,D]
  const float* a = (const float*)d_in[2];  // a   [K,D]
  float* out = (float*)d_out;              // [B,K] fp32

  char* ws = (char*)d_ws;
  float* uu = (float*)(ws + 0);
  float* nua = (float*)(ws + 8192);
  float* an = (float*)(ws + 16384);
  float* vv = (float*)(ws + 24576);
  unsigned short* xb = (unsigned short*)(ws + 25088);
  unsigned short* pb = (unsigned short*)(ws + 156160);
  unsigned short* ab = (unsigned short*)(ws + 2253312);

  prep_kernel<<<(K_SZ + B_SZ) / 4, 256, 0, stream>>>(x, p, a, uu, nua, an, vv,
                                                     xb, pb, ab);
  mfma_kernel<<<(B_SZ / 16) * (K_SZ / 16), 256, 0, stream>>>(
      xb, pb, ab, uu, nua, an, vv, out);
}

// Round 4
// 67.026 us; speedup vs baseline: 1.3557x; 1.0438x over previous
//
#include <hip/hip_runtime.h>
#include <hip/hip_bf16.h>

// Problem constants (reference: B=128, K=2048, D=512, c=1.0)
#define B_SZ 128
#define K_SZ 2048
#define D_SZ 512
#define ROWP 520  // padded LDS row stride in bf16 (1040 B = 65 x 16B chunks,
                  // 65 % 8 == 1 -> 16 rows cycle all 8 bank-quads: b128
                  // fragment reads are perfectly bank-balanced)

typedef __attribute__((ext_vector_type(8))) short short8;   // 8 bf16
typedef __attribute__((ext_vector_type(4))) float floatx4;  // MFMA acc

// Manual RNE fp32 -> bf16.
static __device__ inline unsigned short f2b(float f) {
  unsigned int u = __float_as_uint(f);
  return (unsigned short)((u + 0x7fffu + ((u >> 16) & 1u)) >> 16);
}

// ONE fused kernel: stage x/p/a tiles fp32->bf16 into LDS while computing
// per-row stats (vv, uu, nua, an) in fp32, then dual bf16-MFMA GEMM
// (<x,p>, <x,a>), partial-combine through LDS, fused hyperbolic-MLR epilogue.
// Block = 32 b x 16 k. Grid = 4 x 128 = 512 blocks = 2/CU (LDS 65.3 KB caps
// at exactly 2). 256 threads = 4 waves: wave w -> m-half (w&1), d-half (w>>1),
// each wave does 8 k-steps x 2 MFMAs on a 16x16 tile.
// blockIdx mapping: kt = blk & 127 -> the 4 m-blocks of one k-tile differ by
// 128 ≡ 0 (mod 8) -> same XCD -> p/a rows hit that XCD's L2 after first touch.
// Fragment layouts (m89/m91-verified):
//   A/B: row = lane&15, d = (lane>>4)*8 + j (16B/lane, row-major == B^T)
//   C/D: n = lane&15, m = (lane>>4)*4 + reg
__global__ __launch_bounds__(256, 2) void fused_kernel(
    const float* __restrict__ x, const float* __restrict__ p,
    const float* __restrict__ a, float* __restrict__ out) {
  __shared__ unsigned short xs[32 * ROWP];   // 33280 B
  __shared__ unsigned short ps[16 * ROWP];   // 16640 B (partials alias here)
  __shared__ unsigned short as_[16 * ROWP];  // 16640 B
  __shared__ float stats[32 + 48];           // vv[32] | uu[16] | nua[16] | an[16]

  const int t = threadIdx.x;
  const int bm = (blockIdx.x >> 7) * 32;   // 4 m-tiles of 32 b
  const int kn = (blockIdx.x & 127) * 16;  // 128 k-tiles of 16 k

  // ---- Phase 0a: stage x (32 rows), vv stats. 8 threads/row, 16 float4 ea.
  {
    const int r = t >> 3, s = t & 7;
    const float4* src = (const float4*)(x + (size_t)(bm + r) * D_SZ);
    float vvp = 0.f;
#pragma unroll
    for (int i = 0; i < 16; ++i) {
      float4 v = src[s + i * 8];
      vvp += v.x * v.x + v.y * v.y + v.z * v.z + v.w * v.w;
      ushort4 c;
      c.x = f2b(v.x); c.y = f2b(v.y); c.z = f2b(v.z); c.w = f2b(v.w);
      *(ushort4*)&xs[r * ROWP + (s + i * 8) * 4] = c;
    }
    vvp += __shfl_xor(vvp, 1, 64);
    vvp += __shfl_xor(vvp, 2, 64);
    vvp += __shfl_xor(vvp, 4, 64);
    if (s == 0) stats[r] = vvp;
  }

  // ---- Phase 0b: stage p,a (16 rows), uu/nua/an stats. 16 thr/row, 8 f4 ea.
  {
    const int r = t >> 4, s = t & 15;
    const float4* sp = (const float4*)(p + (size_t)(kn + r) * D_SZ);
    const float4* sa = (const float4*)(a + (size_t)(kn + r) * D_SZ);
    float pp = 0.f, pa = 0.f, aa = 0.f;
#pragma unroll
    for (int i = 0; i < 8; ++i) {
      float4 pv = sp[s + i * 16];
      float4 av = sa[s + i * 16];
      pp += pv.x * pv.x + pv.y * pv.y + pv.z * pv.z + pv.w * pv.w;
      pa += pv.x * av.x + pv.y * av.y + pv.z * av.z + pv.w * av.w;
      aa += av.x * av.x + av.y * av.y + av.z * av.z + av.w * av.w;
      ushort4 pc, ac;
      pc.x = f2b(pv.x); pc.y = f2b(pv.y); pc.z = f2b(pv.z); pc.w = f2b(pv.w);
      ac.x = f2b(av.x); ac.y = f2b(av.y); ac.z = f2b(av.z); ac.w = f2b(av.w);
      *(ushort4*)&ps[r * ROWP + (s + i * 16) * 4] = pc;
      *(ushort4*)&as_[r * ROWP + (s + i * 16) * 4] = ac;
    }
    pp += __shfl_xor(pp, 1, 64);
    pa += __shfl_xor(pa, 1, 64);
    aa += __shfl_xor(aa, 1, 64);
    pp += __shfl_xor(pp, 2, 64);
    pa += __shfl_xor(pa, 2, 64);
    aa += __shfl_xor(aa, 2, 64);
    pp += __shfl_xor(pp, 4, 64);
    pa += __shfl_xor(pa, 4, 64);
    aa += __shfl_xor(aa, 4, 64);
    pp += __shfl_xor(pp, 8, 64);
    pa += __shfl_xor(pa, 8, 64);
    aa += __shfl_xor(aa, 8, 64);
    if (s == 0) {
      stats[32 + r] = pp;        // uu
      stats[48 + r] = -pa;       // nua
      stats[64 + r] = sqrtf(aa); // an
    }
  }
  __syncthreads();

  // ---- Phase 1: dual MFMA. wave w: m-half wm = w&1, d-half dh = w>>1.
  const int w = t >> 6, lane = t & 63;
  const int row16 = lane & 15, quad = lane >> 4;
  const int wm = w & 1, dh = w >> 1;
  const unsigned short* xrow = &xs[(wm * 16 + row16) * ROWP + dh * 256 + quad * 8];
  const unsigned short* prow = &ps[row16 * ROWP + dh * 256 + quad * 8];
  const unsigned short* arow = &as_[row16 * ROWP + dh * 256 + quad * 8];
  floatx4 cs = {0.f, 0.f, 0.f, 0.f};
  floatx4 ca = {0.f, 0.f, 0.f, 0.f};
#pragma unroll
  for (int dc = 0; dc < 8; ++dc) {
    short8 af = *(const short8*)(xrow + dc * 32);
    short8 bp = *(const short8*)(prow + dc * 32);
    short8 bv = *(const short8*)(arow + dc * 32);
    cs = __builtin_amdgcn_mfma_f32_16x16x32_bf16(af, bp, cs, 0, 0, 0);
    ca = __builtin_amdgcn_mfma_f32_16x16x32_bf16(af, bv, ca, 0, 0, 0);
  }

  // ---- Phase 2: combine d-halves through LDS (alias ps; done reading it).
  __syncthreads();
  float* part_s = (float*)ps;          // [4 waves][64 lanes][4 regs] = 4 KB
  float* part_a = part_s + 1024;       // 4 KB
  *(floatx4*)&part_s[(w * 64 + lane) * 4] = cs;
  *(floatx4*)&part_a[(w * 64 + lane) * 4] = ca;
  __syncthreads();

  // ---- Phase 3: epilogue, 2 outputs per thread (c = 1).
#pragma unroll
  for (int o = 0; o < 2; ++o) {
    const int idx = t + o * 256;   // 0..511 -> (m16, n)
    const int m16 = idx >> 4;      // 0..31 local b
    const int n = idx & 15;        // local k
    const int wmI = m16 >> 4, mr = m16 & 15;
    const int lsrc = ((mr >> 2) << 4) | n;
    const int reg = mr & 3;
    const float sdot = part_s[(wmI * 64 + lsrc) * 4 + reg] +
                       part_s[((2 + wmI) * 64 + lsrc) * 4 + reg];
    const float adot = part_a[(wmI * 64 + lsrc) * 4 + reg] +
                       part_a[((2 + wmI) * 64 + lsrc) * 4 + reg];
    const float vvb = stats[m16];
    const float uuk = stats[32 + n];
    const float nuak = stats[48 + n];
    const float ank = stats[64 + n];
    const float beta = 1.f - uuk;            // 1 - c*||p||^2
    const float scale = (2.f / beta) * ank;  // lam_p * ||a||
    const float uv = -sdot;                  // <u,x> = -<p,x>
    const float alpha = 1.f + 2.f * uv + vvb;
    const float den = 1.f + 2.f * uv + uuk * vvb;
    const float inv = 1.f / den;
    const float wwn =
        (alpha * alpha * uuk + 2.f * alpha * beta * uv + beta * beta * vvb) *
        inv * inv;
    const float wa = (alpha * nuak + beta * adot) * inv;
    const float z = 2.f * wa / (ank * (1.f - wwn));
    out[(size_t)(bm + m16) * K_SZ + (kn + n)] = scale * asinhf(z);
  }
}

extern "C" void kernel_launch(void* const* d_in, const int* in_sizes, int n_in,
                              void* d_out, int out_size, void* d_ws, size_t ws_size,
                              hipStream_t stream) {
  const float* x = (const float*)d_in[0];  // inp [B,D]
  const float* p = (const float*)d_in[1];  // p   [K,D]
  const float* a = (const float*)d_in[2];  // a   [K,D]
  float* out = (float*)d_out;              // [B,K] fp32
  (void)d_ws; (void)ws_size;               // no workspace needed

  fused_kernel<<<(B_SZ / 32) * (K_SZ / 16), 256, 0, stream>>>(x, p, a, out);
}